// Round 7
// baseline (302.422 us; speedup 1.0000x reference)
//
#include <hip/hip_runtime.h>
#include <math.h>

#define N_NODES 100000
#define N_EDGES 400000
#define NG 2048
#define H 128
#define NV 100
#define NLAYERS 3
#define SLOPE 0.2f

// scal layout (64 floats = 256 B, all zeroed). Cross-XCD rule (R11 lesson):
// never mix atomic and plain stores on one 128B line within a dispatch.
//  [0]      ea_sum        (atomic, k_prep)
//  [32..34] dot_l         (atomic, k_prep)
//  [48]     alloc counter (atomic, k_alloc)
#define SCAL_N 64

typedef __attribute__((ext_vector_type(8))) short bf16x8;
typedef __attribute__((ext_vector_type(4))) float f32x4;

__device__ __forceinline__ float wave_reduce_sum(float v){
  #pragma unroll
  for (int off = 32; off > 0; off >>= 1) v += __shfl_xor(v, off, 64);
  return v;
}
__device__ __forceinline__ unsigned short rne_bf16(float f){
  unsigned int u = __float_as_uint(f);
  u += 0x7FFF + ((u >> 16) & 1);
  return (unsigned short)(u >> 16);
}
__device__ __forceinline__ unsigned int pack_bf16x2(float lo, float hi){
  return ((unsigned int)rne_bf16(hi) << 16) | rne_bf16(lo);
}

// ---- fused prep: convW | convE | out_init | dots | ea_sum | deg+rank --------
#define PB_CONVW 320                    // 5*16384/256 (single RNE plane)
#define PB_CONVE (PB_CONVW + 50)        // NV*H/256
#define PB_OUT   (PB_CONVE + 8)         // NG/256
#define PB_DOTS  (PB_OUT + 1)           // 3 waves in one block
#define PB_EASUM (PB_DOTS + 256)
#define PB_DEG   (PB_EASUM + 1954)      // (E+N)/256
__global__ __launch_bounds__(256) void k_prep(
    const float* __restrict__ gat_W, const float* __restrict__ lin_W,
    unsigned short* __restrict__ Wf,
    const float* __restrict__ emb, unsigned short* __restrict__ embb,
    const float* __restrict__ ea, const float* __restrict__ ew,
    const float* __restrict__ ae, float* __restrict__ scal,
    const float* __restrict__ wp_b, float* __restrict__ out,
    const int* __restrict__ ei, int* __restrict__ deg,
    int* __restrict__ rank)
{
  int b = blockIdx.x, tid = threadIdx.x;
  if (b < PB_CONVW){
    // W -> RNE bf16, MFMA B-fragment order:
    // idx = m*16384 + k0i*4096 + ct*512 + lane*8 + j
    // k = k0i*32 + (lane>>4)*8 + j, n = ct*16 + (lane&15)
    int i = b*256 + tid;
    int m   = i >> 14;
    int r   = i & 16383;
    int k0i = r >> 12;
    int r3  = r & 4095;
    int ct  = r3 >> 9;
    int r4  = r3 & 511;
    int lane= r4 >> 3;
    int j   = r4 & 7;
    int q = lane >> 4, ln = lane & 15;
    int k = k0i*32 + q*8 + j;
    int n = ct*16 + ln;
    const float* src = (m < 3) ? (gat_W + m*16384) : (lin_W + (m-3)*16384);
    Wf[i] = rne_bf16(src[k*H + n]);
  } else if (b < PB_CONVE){
    int i = (b - PB_CONVW)*256 + tid;
    if (i < NV*H) embb[i] = rne_bf16(emb[i]);
  } else if (b < PB_OUT){
    int g = (b - PB_CONVE)*256 + tid;
    if (g < NG) out[g] = wp_b[0];
  } else if (b < PB_DOTS){
    int l = tid >> 6, ln = tid & 63;
    if (l < NLAYERS){
      float p = ew[l*H + ln]*ae[l*H + ln] + ew[l*H + ln + 64]*ae[l*H + ln + 64];
      p = wave_reduce_sum(p);
      if (ln == 0) atomicAdd(&scal[32 + l], p);
    }
  } else if (b < PB_EASUM){
    int i = (b - PB_DOTS)*256 + tid;
    int stride = 256*256;
    float v = 0.f;
    for (; i < N_EDGES; i += stride) v += ea[i];
    v = wave_reduce_sum(v);
    if ((tid & 63) == 0) atomicAdd(&scal[0], v);
  } else {
    // deg count; the return value IS the edge's rank within its dst bucket —
    // stored so k_scatter needs no second atomic pass.
    int i = (b - PB_EASUM)*256 + tid;
    if (i < N_EDGES + N_NODES){
      int d = (i < N_EDGES) ? ei[N_EDGES + i] : (i - N_EDGES);
      rank[i] = atomicAdd(&deg[d], 1);
    }
  }
}

// ---- alloc (block scan + one atomic) | fused vocab GEMM ---------------------
// Layer-0 projection has only NV=100 distinct rows: one extra block runs the
// EXACT k_gemm instruction sequence on the 100 vocab rows (same fragments ->
// same MFMA bits -> same epilogue reduce order => bitwise identical to the
// old full-N gemm), producing xt0b + per-vocab a_s/a_d tables. The full-N
// result is then a gather-copy (fused into k_scatter).
#define NALLOC ((N_NODES + 255)/256)    // 391
__global__ __launch_bounds__(256) void k_alloc(
    const int* __restrict__ deg, int* __restrict__ row_ptr, int* __restrict__ counter,
    const unsigned short* __restrict__ embb, const unsigned short* __restrict__ Wf,
    unsigned short* __restrict__ xt0b, const float* __restrict__ att1,
    const float* __restrict__ att2, float* __restrict__ tabS, float* __restrict__ tabD)
{
  __shared__ unsigned short lw[16384];
  __shared__ int wsum[4];
  __shared__ int base_s;
  if (blockIdx.x < NALLOC){
    int n = blockIdx.x * 256 + threadIdx.x;
    int d = (n < N_NODES) ? deg[n] : 0;
    int lane = threadIdx.x & 63, wid = threadIdx.x >> 6;
    int v = d;
    #pragma unroll
    for (int off = 1; off < 64; off <<= 1){
      int u = __shfl_up(v, off, 64);
      if (lane >= off) v += u;
    }
    if (lane == 63) wsum[wid] = v;
    __syncthreads();
    if (threadIdx.x == 0){
      int t0 = wsum[0], t1 = wsum[1], t2 = wsum[2], t3 = wsum[3];
      base_s = atomicAdd(counter, t0 + t1 + t2 + t3);
      wsum[0] = 0; wsum[1] = t0; wsum[2] = t0 + t1; wsum[3] = t0 + t1 + t2;
    }
    __syncthreads();
    if (n < N_NODES) row_ptr[n] = base_s + wsum[wid] + (v - d);
    return;
  }

  // ---- vocab GEMM block (blockIdx.x == NALLOC) ----
  int tid  = threadIdx.x;
  int w    = tid >> 6;
  int lane = tid & 63;
  int q    = lane >> 4;
  int ln   = lane & 15;
  int waveRow = w*32;

  #pragma unroll
  for (int i = 0; i < 8; ++i){
    int base = (i*256 + w*64) * 8;
    __builtin_amdgcn_global_load_lds(
        (const __attribute__((address_space(1))) unsigned int*)(Wf + base + lane*8),
        (__attribute__((address_space(3))) unsigned int*)(lw + base),
        16, 0, 0);
  }
  bf16x8 af[2][4];
  #pragma unroll
  for (int m = 0; m < 2; ++m){
    int r = waveRow + m*16 + ln;
    if (r >= NV) r = NV - 1;                 // same clamp pattern as k_gemm
    const unsigned short* Ar = embb + (size_t)r*H;
    #pragma unroll
    for (int k0i = 0; k0i < 4; ++k0i)
      af[m][k0i] = *(const bf16x8*)(Ar + k0i*32 + q*8);
  }
  __syncthreads();

  f32x4 acc[2][8];
  #pragma unroll
  for (int m = 0; m < 2; ++m)
    #pragma unroll
    for (int ct = 0; ct < 8; ++ct) acc[m][ct] = (f32x4){0.f,0.f,0.f,0.f};
  #pragma unroll
  for (int k0i = 0; k0i < 4; ++k0i){
    #pragma unroll
    for (int ct = 0; ct < 8; ++ct){
      bf16x8 bw = *(const bf16x8*)(lw + k0i*4096 + ct*512 + lane*8);
      #pragma unroll
      for (int m = 0; m < 2; ++m)
        acc[m][ct] = __builtin_amdgcn_mfma_f32_16x16x32_bf16(af[m][k0i], bw, acc[m][ct], 0,0,0);
    }
  }

  float as_l[8], ad_l[8];
  #pragma unroll
  for (int ct = 0; ct < 8; ++ct){ as_l[ct] = att1[ct*16+ln]; ad_l[ct] = att2[ct*16+ln]; }
  #pragma unroll
  for (int m = 0; m < 2; ++m){
    #pragma unroll
    for (int r = 0; r < 4; ++r){
      int grow = waveRow + m*16 + q*4 + r;
      bool ok = grow < NV;
      float ps = 0.f, pd = 0.f;
      #pragma unroll
      for (int ct = 0; ct < 8; ++ct){
        float v = acc[m][ct][r];
        if (ok) xt0b[(size_t)grow*H + ct*16 + ln] = rne_bf16(v);
        ps += v * as_l[ct]; pd += v * ad_l[ct];
      }
      #pragma unroll
      for (int mk = 8; mk > 0; mk >>= 1){
        ps += __shfl_xor(ps, mk, 64);
        pd += __shfl_xor(pd, mk, 64);
      }
      if (ok && ln == 0){ tabS[grow] = ps; tabD[grow] = pd; }
    }
  }
}

// ---- scatter (atomic-free, rank-based) | fused layer-0 gather ---------------
#define NSCAT ((N_EDGES + N_NODES + 255)/256)   // 1954
__global__ void k_scatter(const int* __restrict__ ei, const float* __restrict__ ea,
                          const float* __restrict__ scal, const int* __restrict__ row_ptr,
                          const int* __restrict__ rank, int* __restrict__ csr_src,
                          float* __restrict__ csr_ea,
                          const int* __restrict__ x, const uint4* __restrict__ xt0b4,
                          const float* __restrict__ tabS, const float* __restrict__ tabD,
                          uint4* __restrict__ xtb4, float* __restrict__ a_s,
                          float* __restrict__ a_d){
  int b = blockIdx.x;
  if (b < NSCAT){
    int i = b * 256 + threadIdx.x;
    if (i >= N_EDGES + N_NODES) return;
    int s, d; float v;
    if (i < N_EDGES){ s = ei[i]; d = ei[N_EDGES + i]; v = ea[i]; }
    else            { s = d = i - N_EDGES; v = scal[0] * (1.0f / N_EDGES); }  // ea_mean
    int pos = row_ptr[d] + rank[i];
    csr_src[pos] = s;
    csr_ea[pos]  = v;
    return;
  }
  // layer-0 gather: xtb[n] = xt0b[x[n]], a_s/a_d from vocab tables
  int gb = b - NSCAT;                        // [0, 6250)
  int t  = threadIdx.x;
  int n  = gb*16 + (t >> 4);                 // 6250*16 = 100000 exact
  int c  = t & 15;
  if (n >= N_NODES) return;                  // defensive (exact at current N)
  int v  = x[n];
  xtb4[(size_t)n*(H/8) + c] = xt0b4[(size_t)v*(H/8) + c];
  if (c == 0)      a_s[n] = tabS[v];
  else if (c == 1) a_d[n] = tabD[v];
}

// ---- MFMA GEMM (layers 1,2): bf16 A, RNE-bf16 W, 32KB W via global_load_lds -
// Block = 256 thr = 4 waves; block tile 128 rows; wave tile 32 rows; 4 blk/CU.
__global__ __launch_bounds__(256, 4) void k_gemm(
    const unsigned short* __restrict__ Ab,
    const unsigned short* __restrict__ Wf,      // fragment-ordered, 16384 ushorts
    unsigned short* __restrict__ Cb,
    const float* __restrict__ att1, const float* __restrict__ att2,
    float* __restrict__ a_s_out, float* __restrict__ a_d_out)
{
  __shared__ unsigned short lw[16384];   // 32 KB single plane
  int tid  = threadIdx.x;
  int w    = tid >> 6;
  int lane = tid & 63;
  int q    = lane >> 4;
  int ln   = lane & 15;
  int waveRow = blockIdx.x*128 + w*32;

  #pragma unroll
  for (int i = 0; i < 8; ++i){
    int base = (i*256 + w*64) * 8;               // ushort offset, wave-uniform
    __builtin_amdgcn_global_load_lds(
        (const __attribute__((address_space(1))) unsigned int*)(Wf + base + lane*8),
        (__attribute__((address_space(3))) unsigned int*)(lw + base),
        16, 0, 0);
  }

  bf16x8 af[2][4];
  #pragma unroll
  for (int m = 0; m < 2; ++m){
    int r = waveRow + m*16 + ln;
    if (r >= N_NODES) r = N_NODES - 1;
    const unsigned short* Ar = Ab + (size_t)r*H;
    #pragma unroll
    for (int k0i = 0; k0i < 4; ++k0i)
      af[m][k0i] = *(const bf16x8*)(Ar + k0i*32 + q*8);
  }
  __syncthreads();   // drains vmcnt (incl. global_load_lds) before ds_read

  f32x4 acc[2][8];
  #pragma unroll
  for (int m = 0; m < 2; ++m)
    #pragma unroll
    for (int ct = 0; ct < 8; ++ct) acc[m][ct] = (f32x4){0.f,0.f,0.f,0.f};

  #pragma unroll
  for (int k0i = 0; k0i < 4; ++k0i){
    #pragma unroll
    for (int ct = 0; ct < 8; ++ct){
      bf16x8 bw = *(const bf16x8*)(lw + k0i*4096 + ct*512 + lane*8);
      #pragma unroll
      for (int m = 0; m < 2; ++m)
        acc[m][ct] = __builtin_amdgcn_mfma_f32_16x16x32_bf16(af[m][k0i], bw, acc[m][ct], 0,0,0);
    }
  }

  float as_l[8], ad_l[8];
  #pragma unroll
  for (int ct = 0; ct < 8; ++ct){ as_l[ct] = att1[ct*16+ln]; ad_l[ct] = att2[ct*16+ln]; }
  #pragma unroll
  for (int m = 0; m < 2; ++m){
    #pragma unroll
    for (int r = 0; r < 4; ++r){
      int grow = waveRow + m*16 + q*4 + r;
      bool ok = grow < N_NODES;
      float ps = 0.f, pd = 0.f;
      #pragma unroll
      for (int ct = 0; ct < 8; ++ct){
        float v = acc[m][ct][r];
        if (ok) Cb[(size_t)grow*H + ct*16 + ln] = rne_bf16(v);
        ps += v * as_l[ct]; pd += v * ad_l[ct];
      }
      #pragma unroll
      for (int mk = 8; mk > 0; mk >>= 1){
        ps += __shfl_xor(ps, mk, 64);
        pd += __shfl_xor(pd, mk, 64);
      }
      if (ok && ln == 0){ a_s_out[grow] = ps; a_d_out[grow] = pd; }
    }
  }
}

// ---- fused dense1+dense2+readout, 32KB LDS / 4 blocks/CU --------------------
// relu1 transpose is wave-local (A2 rows lr = w*32+m*16+ln are within the
// wave's own 32 rows); slab lives inside dead lw. XOR-swizzle col^((lr&7)<<3).
__global__ __launch_bounds__(256, 4) void k_dense(
    const unsigned short* __restrict__ Ab,      // hb
    const unsigned short* __restrict__ Wf,      // W3 plane; W4 = Wf + 16384
    const float* __restrict__ b1, const float* __restrict__ b2,
    const float* __restrict__ wp, const int* __restrict__ batch,
    float* __restrict__ out)
{
  __shared__ unsigned short lw[16384];   // W3 -> relu1 slabs -> W4
  int tid  = threadIdx.x;
  int w    = tid >> 6;
  int lane = tid & 63;
  int q    = lane >> 4;
  int ln   = lane & 15;
  int waveRow = blockIdx.x*128 + w*32;

  // stage W3
  #pragma unroll
  for (int i = 0; i < 8; ++i){
    int base = (i*256 + w*64) * 8;
    __builtin_amdgcn_global_load_lds(
        (const __attribute__((address_space(1))) unsigned int*)(Wf + base + lane*8),
        (__attribute__((address_space(3))) unsigned int*)(lw + base),
        16, 0, 0);
  }
  bf16x8 af[2][4];
  #pragma unroll
  for (int m = 0; m < 2; ++m){
    int r = waveRow + m*16 + ln;
    if (r >= N_NODES) r = N_NODES - 1;
    const unsigned short* Ar = Ab + (size_t)r*H;
    #pragma unroll
    for (int k0i = 0; k0i < 4; ++k0i)
      af[m][k0i] = *(const bf16x8*)(Ar + k0i*32 + q*8);
  }
  __syncthreads();   // drains vmcnt -> W3 resident

  f32x4 acc[2][8];
  #pragma unroll
  for (int m = 0; m < 2; ++m)
    #pragma unroll
    for (int ct = 0; ct < 8; ++ct) acc[m][ct] = (f32x4){0.f,0.f,0.f,0.f};
  #pragma unroll
  for (int k0i = 0; k0i < 4; ++k0i){
    #pragma unroll
    for (int ct = 0; ct < 8; ++ct){
      bf16x8 bw = *(const bf16x8*)(lw + k0i*4096 + ct*512 + lane*8);
      #pragma unroll
      for (int m = 0; m < 2; ++m)
        acc[m][ct] = __builtin_amdgcn_mfma_f32_16x16x32_bf16(af[m][k0i], bw, acc[m][ct], 0,0,0);
    }
  }
  __syncthreads();   // all waves done reading W3 -> lw reusable

  // epilogue1: relu(acc + b1) -> per-wave 8KB slab (swizzled bf16)
  unsigned short* lh = lw + (w << 12);   // 4096 ushorts, wave-local rows 0..31
  float b1_l[8];
  #pragma unroll
  for (int ct = 0; ct < 8; ++ct) b1_l[ct] = b1[ct*16+ln];
  #pragma unroll
  for (int m = 0; m < 2; ++m){
    #pragma unroll
    for (int r = 0; r < 4; ++r){
      int lr = m*16 + q*4 + r;
      int sw = (lr & 7) << 3;
      #pragma unroll
      for (int ct = 0; ct < 8; ++ct){
        int col = ct*16 + ln;
        lh[lr*128 + (col ^ sw)] = rne_bf16(fmaxf(acc[m][ct][r] + b1_l[ct], 0.f));
      }
    }
  }
  __syncthreads();   // cross-lane LDS ordering (write -> read)

  // A2 fragments from slab (swizzled read, 16B-aligned b128)
  bf16x8 af2[2][4];
  #pragma unroll
  for (int m = 0; m < 2; ++m){
    int lr = m*16 + ln;
    int sw = (lr & 7) << 3;
    #pragma unroll
    for (int k0i = 0; k0i < 4; ++k0i)
      af2[m][k0i] = *(const bf16x8*)(lh + lr*128 + ((k0i*32 + q*8) ^ sw));
  }
  __syncthreads();   // all af2 reads done -> lw reusable for W4

  // stage W4 over lw
  #pragma unroll
  for (int i = 0; i < 8; ++i){
    int base = (i*256 + w*64) * 8;
    __builtin_amdgcn_global_load_lds(
        (const __attribute__((address_space(1))) unsigned int*)(Wf + 16384 + base + lane*8),
        (__attribute__((address_space(3))) unsigned int*)(lw + base),
        16, 0, 0);
  }
  __syncthreads();   // drains vmcnt -> W4 resident

  #pragma unroll
  for (int m = 0; m < 2; ++m)
    #pragma unroll
    for (int ct = 0; ct < 8; ++ct) acc[m][ct] = (f32x4){0.f,0.f,0.f,0.f};
  #pragma unroll
  for (int k0i = 0; k0i < 4; ++k0i){
    #pragma unroll
    for (int ct = 0; ct < 8; ++ct){
      bf16x8 bw = *(const bf16x8*)(lw + k0i*4096 + ct*512 + lane*8);
      #pragma unroll
      for (int m = 0; m < 2; ++m)
        acc[m][ct] = __builtin_amdgcn_mfma_f32_16x16x32_bf16(af2[m][k0i], bw, acc[m][ct], 0,0,0);
    }
  }

  // epilogue2: relu(acc + b2) . wp -> atomicAdd out[batch[row]]
  float b2_l[8], wp_l[8];
  #pragma unroll
  for (int ct = 0; ct < 8; ++ct){ b2_l[ct] = b2[ct*16+ln]; wp_l[ct] = wp[ct*16+ln]; }
  #pragma unroll
  for (int m = 0; m < 2; ++m){
    #pragma unroll
    for (int r = 0; r < 4; ++r){
      int grow = waveRow + m*16 + q*4 + r;
      bool ok = grow < N_NODES;
      float ps = 0.f;
      #pragma unroll
      for (int ct = 0; ct < 8; ++ct)
        ps += fmaxf(acc[m][ct][r] + b2_l[ct], 0.f) * wp_l[ct];
      #pragma unroll
      for (int mk = 8; mk > 0; mk >>= 1) ps += __shfl_xor(ps, mk, 64);
      if (ok && ln == 0) atomicAdd(&out[batch[grow]], ps);
    }
  }
}

// ---- aggregate: FOUR nodes per wave, 8 cols/lane, shuffle-staged ------------
// vs R5: (a) ls_s/ls_w LDS staging replaced by __shfl broadcasts (removes the
// ds_write->lgkmcnt->ds_read round-trip from the critical path; all lanes of a
// quarter need the SAME staged value = broadcast); (b) BOTH 8-row gather
// groups issued up front, before the a_s-gather+exp chain (was: group 1
// issued after group 0 consumed -> one exposed ~500cy L3 round-trip whenever
// maxd>8). Consumption order unchanged -> bitwise-identical results.
// VGPR ~95 (<=128, 4 waves/SIMD); no LDS.
__global__ __launch_bounds__(256, 4) void k_aggregate(
    const uint4* __restrict__ xtb4, const float* __restrict__ a_s,
    const float* __restrict__ a_d, const int* __restrict__ csr_src,
    const float* __restrict__ csr_ea, const int* __restrict__ row_ptr,
    const int* __restrict__ deg, const float* __restrict__ scal, int l,
    const float* __restrict__ bias, uint4* __restrict__ hb4)
{
  int lane = threadIdx.x & 63;
  int h    = lane >> 4;          // quarter 0..3
  int c    = lane & 15;          // col group: cols 8c..8c+7
  int wid  = threadIdx.x >> 6;
  int n    = blockIdx.x*16 + wid*4 + h;   // 6250*16 = 100000 exact
  if (n >= N_NODES) return;               // defensive (exact at current N)
  int beg = row_ptr[n];
  int d   = deg[n];              // >= 1 (self loop)
  float adn = a_d[n];
  float dl  = scal[32 + l];
  int v = d;
  v = max(v, __shfl_xor(v, 16, 64));
  v = max(v, __shfl_xor(v, 32, 64));
  int maxd = v;                  // wave-shared loop bound
  int hq = h << 4;               // quarter base lane

  float4 acA = make_float4(0.f,0.f,0.f,0.f);
  float4 acB = make_float4(0.f,0.f,0.f,0.f);
  float ss = 0.f;
  for (int base = 0; base < maxd; base += 16){
    int j = base + c;
    bool vld = (j < d);
    int s = 0; float eaj = 0.f;
    if (vld){
      int e = beg + j;
      s   = csr_src[e];                        // coalesced per quarter
      eaj = csr_ea[e];
    }
    int cnt = (min(16, maxd - base) + 7) & ~7;
    bool two = (cnt > 8);                      // wave-uniform

    // issue ALL row gathers up front (shuffle-broadcast the sources)
    uint4 xv0[8], xv1[8];
    #pragma unroll
    for (int u = 0; u < 8; ++u){
      int su = __shfl(s, hq + u, 64);
      xv0[u] = xtb4[(size_t)su*(H/8) + c];
    }
    if (two){
      #pragma unroll
      for (int u = 0; u < 8; ++u){
        int su = __shfl(s, hq + 8 + u, 64);
        xv1[u] = xtb4[(size_t)su*(H/8) + c];
      }
    }

    // wgt chain (a_s gather + exp) overlaps the in-flight gathers
    float wgt = 0.f;
    if (vld){
      float lg = a_s[s] + adn + dl*eaj;        // unstabilized exp is exact math
      lg = (lg > 0.f) ? lg : SLOPE*lg;
      wgt = __expf(lg);
    }

    #pragma unroll
    for (int u = 0; u < 8; ++u){
      float wg = __shfl(wgt, hq + u, 64);
      acA.x += wg * __uint_as_float(xv0[u].x << 16);
      acA.y += wg * __uint_as_float(xv0[u].x & 0xFFFF0000u);
      acA.z += wg * __uint_as_float(xv0[u].y << 16);
      acA.w += wg * __uint_as_float(xv0[u].y & 0xFFFF0000u);
      acB.x += wg * __uint_as_float(xv0[u].z << 16);
      acB.y += wg * __uint_as_float(xv0[u].z & 0xFFFF0000u);
      acB.z += wg * __uint_as_float(xv0[u].w << 16);
      acB.w += wg * __uint_as_float(xv0[u].w & 0xFFFF0000u);
      ss    += wg;
    }
    if (two){
      #pragma unroll
      for (int u = 0; u < 8; ++u){
        float wg = __shfl(wgt, hq + 8 + u, 64);
        acA.x += wg * __uint_as_float(xv1[u].x << 16);
        acA.y += wg * __uint_as_float(xv1[u].x & 0xFFFF0000u);
        acA.z += wg * __uint_as_float(xv1[u].y << 16);
        acA.w += wg * __uint_as_float(xv1[u].y & 0xFFFF0000u);
        acB.x += wg * __uint_as_float(xv1[u].z << 16);
        acB.y += wg * __uint_as_float(xv1[u].z & 0xFFFF0000u);
        acB.z += wg * __uint_as_float(xv1[u].w << 16);
        acB.w += wg * __uint_as_float(xv1[u].w & 0xFFFF0000u);
        ss    += wg;
      }
    }
  }

  float4 bvA = *(const float4*)(bias + c*8);
  float4 bvB = *(const float4*)(bias + c*8 + 4);
  float inv = 1.0f / ss;
  acA.x = acA.x*inv + bvA.x;
  acA.y = acA.y*inv + bvA.y;
  acA.z = acA.z*inv + bvA.z;
  acA.w = acA.w*inv + bvA.w;
  acB.x = acB.x*inv + bvB.x;
  acB.y = acB.y*inv + bvB.y;
  acB.z = acB.z*inv + bvB.z;
  acB.w = acB.w*inv + bvB.w;
  float sq = acA.x*acA.x + acA.y*acA.y + acA.z*acA.z + acA.w*acA.w
           + acB.x*acB.x + acB.y*acB.y + acB.z*acB.z + acB.w*acB.w;
  #pragma unroll
  for (int off = 8; off > 0; off >>= 1) sq += __shfl_xor(sq, off, 64);  // within quarter
  float rn = 1.0f / fmaxf(sqrtf(sq), 1e-12f);
  uint4 o;
  o.x = pack_bf16x2(acA.x*rn, acA.y*rn);
  o.y = pack_bf16x2(acA.z*rn, acA.w*rn);
  o.z = pack_bf16x2(acB.x*rn, acB.y*rn);
  o.w = pack_bf16x2(acB.z*rn, acB.w*rn);
  hb4[(size_t)n*(H/8) + c] = o;
}

// ---- launch -----------------------------------------------------------------
extern "C" void kernel_launch(void* const* d_in, const int* in_sizes, int n_in,
                              void* d_out, int out_size, void* d_ws, size_t ws_size,
                              hipStream_t stream) {
  const int*   x          = (const int*)  d_in[0];
  const int*   edge_index = (const int*)  d_in[1];
  const float* edge_attr  = (const float*)d_in[2];
  const int*   batch      = (const int*)  d_in[3];
  const float* emb        = (const float*)d_in[4];
  const float* gat_W      = (const float*)d_in[5];
  const float* att_src    = (const float*)d_in[6];
  const float* att_dst    = (const float*)d_in[7];
  const float* edge_W     = (const float*)d_in[8];
  const float* att_edge   = (const float*)d_in[9];
  const float* gat_b      = (const float*)d_in[10];
  const float* lin_W      = (const float*)d_in[11];
  const float* lin_b      = (const float*)d_in[12];
  const float* wp_W       = (const float*)d_in[13];
  const float* wp_b       = (const float*)d_in[14];
  float* out = (float*)d_out;

  // workspace layout — 16B-aligned bf16 arrays first, then 4B arrays
  unsigned short* hb  = (unsigned short*)d_ws;          // N*H bf16
  unsigned short* xtb = hb + (size_t)N_NODES*H;         // N*H bf16
  unsigned short* Wt  = xtb + (size_t)N_NODES*H;        // 5*16384 (RNE single plane)
  unsigned short* embb= Wt + 5*16384;                   // NV*H
  unsigned short* xt0b= embb + NV*H;                    // NV*H (vocab layer-0 rows)
  float* tabS   = (float*)(xt0b + NV*H);                // NV
  float* tabD   = tabS + NV;                            // NV
  float* a_s    = tabD + NV;                            // N
  float* a_d    = a_s + N_NODES;                        // N
  float* csr_ea = a_d + N_NODES;                        // E+N
  float* scal   = csr_ea + (N_EDGES + N_NODES);         // SCAL_N (zeroed)
  int*   deg    = (int*)(scal + SCAL_N);                // N (zeroed)
  int*   rank   = deg + N_NODES;                        // E+N
  int*   row_ptr= rank + (N_EDGES + N_NODES);           // N
  int*   csr_src= row_ptr + N_NODES;                    // E+N

  hipMemsetAsync(scal, 0, (size_t)(SCAL_N + N_NODES) * sizeof(float), stream);

  k_prep<<<PB_DEG, 256, 0, stream>>>(
      gat_W, lin_W, Wt, emb, embb, edge_attr, edge_W, att_edge, scal,
      wp_b, out, edge_index, deg, rank);
  // alloc scan + fused vocab layer-0 GEMM (1 extra block)
  k_alloc<<<NALLOC + 1, 256, 0, stream>>>(
      deg, row_ptr, (int*)&scal[48],
      embb, Wt, xt0b, att_src, att_dst, tabS, tabD);
  // scatter + fused layer-0 gather (xtb[n] = xt0b[x[n]], a_s/a_d tables)
  k_scatter<<<NSCAT + (N_NODES/16), 256, 0, stream>>>(
      edge_index, edge_attr, scal, row_ptr, rank, csr_src, csr_ea,
      x, (const uint4*)xt0b, tabS, tabD, (uint4*)xtb, a_s, a_d);

  const int gemm_grid = (N_NODES + 127) / 128;
  for (int l = 0; l < NLAYERS; ++l){
    if (l > 0)
      k_gemm<<<gemm_grid, 256, 0, stream>>>(
          hb, Wt + (size_t)l*16384, xtb,
          att_src + l*H, att_dst + l*H, a_s, a_d);
    k_aggregate<<<(N_NODES + 15)/16, 256, 0, stream>>>(
        (const uint4*)xtb, a_s, a_d, csr_src, csr_ea, row_ptr, deg,
        scal, l, gat_b + l*H, (uint4*)hb);
  }
  // fused dense1 + dense2 + readout (32KB LDS, 4 blocks/CU)
  k_dense<<<gemm_grid, 256, 0, stream>>>(
      hb, Wt + (size_t)3*16384, lin_b, lin_b + H, wp_W, batch, out);
}

// Round 8
// 295.700 us; speedup vs baseline: 1.0227x; 1.0227x over previous
//
#include <hip/hip_runtime.h>
#include <math.h>

#define N_NODES 100000
#define N_EDGES 400000
#define NG 2048
#define H 128
#define NV 100
#define NLAYERS 3
#define SLOPE 0.2f

// scal layout (64 floats = 256 B, all zeroed). Cross-XCD rule (R11 lesson):
// never mix atomic and plain stores on one 128B line within a dispatch.
//  [0]      ea_sum        (atomic, k_prep)
//  [32..34] dot_l         (atomic, k_prep)
//  [48]     alloc counter (atomic, k_alloc)
#define SCAL_N 64

typedef __attribute__((ext_vector_type(8))) short bf16x8;
typedef __attribute__((ext_vector_type(4))) float f32x4;

__device__ __forceinline__ float wave_reduce_sum(float v){
  #pragma unroll
  for (int off = 32; off > 0; off >>= 1) v += __shfl_xor(v, off, 64);
  return v;
}
__device__ __forceinline__ unsigned short rne_bf16(float f){
  unsigned int u = __float_as_uint(f);
  u += 0x7FFF + ((u >> 16) & 1);
  return (unsigned short)(u >> 16);
}
__device__ __forceinline__ unsigned int pack_bf16x2(float lo, float hi){
  return ((unsigned int)rne_bf16(hi) << 16) | rne_bf16(lo);
}

// ---- fused prep: convW | convE | out_init | dots | ea_sum | deg+rank --------
#define PB_CONVW 320                    // 5*16384/256 (single RNE plane)
#define PB_CONVE (PB_CONVW + 50)        // NV*H/256
#define PB_OUT   (PB_CONVE + 8)         // NG/256
#define PB_DOTS  (PB_OUT + 1)           // 3 waves in one block
#define PB_EASUM (PB_DOTS + 256)
#define PB_DEG   (PB_EASUM + 1954)      // (E+N)/256
__global__ __launch_bounds__(256) void k_prep(
    const float* __restrict__ gat_W, const float* __restrict__ lin_W,
    unsigned short* __restrict__ Wf,
    const float* __restrict__ emb, unsigned short* __restrict__ embb,
    const float* __restrict__ ea, const float* __restrict__ ew,
    const float* __restrict__ ae, float* __restrict__ scal,
    const float* __restrict__ wp_b, float* __restrict__ out,
    const int* __restrict__ ei, int* __restrict__ deg,
    int* __restrict__ rank)
{
  int b = blockIdx.x, tid = threadIdx.x;
  if (b < PB_CONVW){
    // W -> RNE bf16, MFMA B-fragment order:
    // idx = m*16384 + k0i*4096 + ct*512 + lane*8 + j
    // k = k0i*32 + (lane>>4)*8 + j, n = ct*16 + (lane&15)
    int i = b*256 + tid;
    int m   = i >> 14;
    int r   = i & 16383;
    int k0i = r >> 12;
    int r3  = r & 4095;
    int ct  = r3 >> 9;
    int r4  = r3 & 511;
    int lane= r4 >> 3;
    int j   = r4 & 7;
    int q = lane >> 4, ln = lane & 15;
    int k = k0i*32 + q*8 + j;
    int n = ct*16 + ln;
    const float* src = (m < 3) ? (gat_W + m*16384) : (lin_W + (m-3)*16384);
    Wf[i] = rne_bf16(src[k*H + n]);
  } else if (b < PB_CONVE){
    int i = (b - PB_CONVW)*256 + tid;
    if (i < NV*H) embb[i] = rne_bf16(emb[i]);
  } else if (b < PB_OUT){
    int g = (b - PB_CONVE)*256 + tid;
    if (g < NG) out[g] = wp_b[0];
  } else if (b < PB_DOTS){
    int l = tid >> 6, ln = tid & 63;
    if (l < NLAYERS){
      float p = ew[l*H + ln]*ae[l*H + ln] + ew[l*H + ln + 64]*ae[l*H + ln + 64];
      p = wave_reduce_sum(p);
      if (ln == 0) atomicAdd(&scal[32 + l], p);
    }
  } else if (b < PB_EASUM){
    int i = (b - PB_DOTS)*256 + tid;
    int stride = 256*256;
    float v = 0.f;
    for (; i < N_EDGES; i += stride) v += ea[i];
    v = wave_reduce_sum(v);
    if ((tid & 63) == 0) atomicAdd(&scal[0], v);
  } else {
    // deg count; the return value IS the edge's rank within its dst bucket —
    // stored so k_scatter needs no second atomic pass.
    int i = (b - PB_EASUM)*256 + tid;
    if (i < N_EDGES + N_NODES){
      int d = (i < N_EDGES) ? ei[N_EDGES + i] : (i - N_EDGES);
      rank[i] = atomicAdd(&deg[d], 1);
    }
  }
}

// ---- alloc (block scan + one atomic) | fused vocab GEMM ---------------------
// Layer-0 projection has only NV=100 distinct rows: one extra block runs the
// EXACT k_gemm instruction sequence on the 100 vocab rows (same fragments ->
// same MFMA bits -> same epilogue reduce order => bitwise identical to the
// old full-N gemm), producing xt0b + per-vocab a_s/a_d tables. The full-N
// result is then a gather-copy (fused into k_scatter). [validated bit-exact R7]
#define NALLOC ((N_NODES + 255)/256)    // 391
__global__ __launch_bounds__(256) void k_alloc(
    const int* __restrict__ deg, int* __restrict__ row_ptr, int* __restrict__ counter,
    const unsigned short* __restrict__ embb, const unsigned short* __restrict__ Wf,
    unsigned short* __restrict__ xt0b, const float* __restrict__ att1,
    const float* __restrict__ att2, float* __restrict__ tabS, float* __restrict__ tabD)
{
  __shared__ unsigned short lw[16384];
  __shared__ int wsum[4];
  __shared__ int base_s;
  if (blockIdx.x < NALLOC){
    int n = blockIdx.x * 256 + threadIdx.x;
    int d = (n < N_NODES) ? deg[n] : 0;
    int lane = threadIdx.x & 63, wid = threadIdx.x >> 6;
    int v = d;
    #pragma unroll
    for (int off = 1; off < 64; off <<= 1){
      int u = __shfl_up(v, off, 64);
      if (lane >= off) v += u;
    }
    if (lane == 63) wsum[wid] = v;
    __syncthreads();
    if (threadIdx.x == 0){
      int t0 = wsum[0], t1 = wsum[1], t2 = wsum[2], t3 = wsum[3];
      base_s = atomicAdd(counter, t0 + t1 + t2 + t3);
      wsum[0] = 0; wsum[1] = t0; wsum[2] = t0 + t1; wsum[3] = t0 + t1 + t2;
    }
    __syncthreads();
    if (n < N_NODES) row_ptr[n] = base_s + wsum[wid] + (v - d);
    return;
  }

  // ---- vocab GEMM block (blockIdx.x == NALLOC) ----
  int tid  = threadIdx.x;
  int w    = tid >> 6;
  int lane = tid & 63;
  int q    = lane >> 4;
  int ln   = lane & 15;
  int waveRow = w*32;

  #pragma unroll
  for (int i = 0; i < 8; ++i){
    int base = (i*256 + w*64) * 8;
    __builtin_amdgcn_global_load_lds(
        (const __attribute__((address_space(1))) unsigned int*)(Wf + base + lane*8),
        (__attribute__((address_space(3))) unsigned int*)(lw + base),
        16, 0, 0);
  }
  bf16x8 af[2][4];
  #pragma unroll
  for (int m = 0; m < 2; ++m){
    int r = waveRow + m*16 + ln;
    if (r >= NV) r = NV - 1;                 // same clamp pattern as k_gemm
    const unsigned short* Ar = embb + (size_t)r*H;
    #pragma unroll
    for (int k0i = 0; k0i < 4; ++k0i)
      af[m][k0i] = *(const bf16x8*)(Ar + k0i*32 + q*8);
  }
  __syncthreads();

  f32x4 acc[2][8];
  #pragma unroll
  for (int m = 0; m < 2; ++m)
    #pragma unroll
    for (int ct = 0; ct < 8; ++ct) acc[m][ct] = (f32x4){0.f,0.f,0.f,0.f};
  #pragma unroll
  for (int k0i = 0; k0i < 4; ++k0i){
    #pragma unroll
    for (int ct = 0; ct < 8; ++ct){
      bf16x8 bw = *(const bf16x8*)(lw + k0i*4096 + ct*512 + lane*8);
      #pragma unroll
      for (int m = 0; m < 2; ++m)
        acc[m][ct] = __builtin_amdgcn_mfma_f32_16x16x32_bf16(af[m][k0i], bw, acc[m][ct], 0,0,0);
    }
  }

  float as_l[8], ad_l[8];
  #pragma unroll
  for (int ct = 0; ct < 8; ++ct){ as_l[ct] = att1[ct*16+ln]; ad_l[ct] = att2[ct*16+ln]; }
  #pragma unroll
  for (int m = 0; m < 2; ++m){
    #pragma unroll
    for (int r = 0; r < 4; ++r){
      int grow = waveRow + m*16 + q*4 + r;
      bool ok = grow < NV;
      float ps = 0.f, pd = 0.f;
      #pragma unroll
      for (int ct = 0; ct < 8; ++ct){
        float v = acc[m][ct][r];
        if (ok) xt0b[(size_t)grow*H + ct*16 + ln] = rne_bf16(v);
        ps += v * as_l[ct]; pd += v * ad_l[ct];
      }
      #pragma unroll
      for (int mk = 8; mk > 0; mk >>= 1){
        ps += __shfl_xor(ps, mk, 64);
        pd += __shfl_xor(pd, mk, 64);
      }
      if (ok && ln == 0){ tabS[grow] = ps; tabD[grow] = pd; }
    }
  }
}

// ---- scatter (atomic-free, rank-based) | fused layer-0 gather ---------------
#define NSCAT ((N_EDGES + N_NODES + 255)/256)   // 1954
__global__ void k_scatter(const int* __restrict__ ei, const float* __restrict__ ea,
                          const float* __restrict__ scal, const int* __restrict__ row_ptr,
                          const int* __restrict__ rank, int* __restrict__ csr_src,
                          float* __restrict__ csr_ea,
                          const int* __restrict__ x, const uint4* __restrict__ xt0b4,
                          const float* __restrict__ tabS, const float* __restrict__ tabD,
                          uint4* __restrict__ xtb4, float* __restrict__ a_s,
                          float* __restrict__ a_d){
  int b = blockIdx.x;
  if (b < NSCAT){
    int i = b * 256 + threadIdx.x;
    if (i >= N_EDGES + N_NODES) return;
    int s, d; float v;
    if (i < N_EDGES){ s = ei[i]; d = ei[N_EDGES + i]; v = ea[i]; }
    else            { s = d = i - N_EDGES; v = scal[0] * (1.0f / N_EDGES); }  // ea_mean
    int pos = row_ptr[d] + rank[i];
    csr_src[pos] = s;
    csr_ea[pos]  = v;
    return;
  }
  // layer-0 gather: xtb[n] = xt0b[x[n]], a_s/a_d from vocab tables
  int gb = b - NSCAT;                        // [0, 6250)
  int t  = threadIdx.x;
  int n  = gb*16 + (t >> 4);                 // 6250*16 = 100000 exact
  int c  = t & 15;
  if (n >= N_NODES) return;                  // defensive (exact at current N)
  int v  = x[n];
  xtb4[(size_t)n*(H/8) + c] = xt0b4[(size_t)v*(H/8) + c];
  if (c == 0)      a_s[n] = tabS[v];
  else if (c == 1) a_d[n] = tabD[v];
}

// ---- MFMA GEMM (layers 1,2): bf16 A, RNE-bf16 W, 32KB W via global_load_lds -
// Block = 256 thr = 4 waves; block tile 128 rows; wave tile 32 rows; 4 blk/CU.
__global__ __launch_bounds__(256, 4) void k_gemm(
    const unsigned short* __restrict__ Ab,
    const unsigned short* __restrict__ Wf,      // fragment-ordered, 16384 ushorts
    unsigned short* __restrict__ Cb,
    const float* __restrict__ att1, const float* __restrict__ att2,
    float* __restrict__ a_s_out, float* __restrict__ a_d_out)
{
  __shared__ unsigned short lw[16384];   // 32 KB single plane
  int tid  = threadIdx.x;
  int w    = tid >> 6;
  int lane = tid & 63;
  int q    = lane >> 4;
  int ln   = lane & 15;
  int waveRow = blockIdx.x*128 + w*32;

  #pragma unroll
  for (int i = 0; i < 8; ++i){
    int base = (i*256 + w*64) * 8;               // ushort offset, wave-uniform
    __builtin_amdgcn_global_load_lds(
        (const __attribute__((address_space(1))) unsigned int*)(Wf + base + lane*8),
        (__attribute__((address_space(3))) unsigned int*)(lw + base),
        16, 0, 0);
  }

  bf16x8 af[2][4];
  #pragma unroll
  for (int m = 0; m < 2; ++m){
    int r = waveRow + m*16 + ln;
    if (r >= N_NODES) r = N_NODES - 1;
    const unsigned short* Ar = Ab + (size_t)r*H;
    #pragma unroll
    for (int k0i = 0; k0i < 4; ++k0i)
      af[m][k0i] = *(const bf16x8*)(Ar + k0i*32 + q*8);
  }
  __syncthreads();   // drains vmcnt (incl. global_load_lds) before ds_read

  f32x4 acc[2][8];
  #pragma unroll
  for (int m = 0; m < 2; ++m)
    #pragma unroll
    for (int ct = 0; ct < 8; ++ct) acc[m][ct] = (f32x4){0.f,0.f,0.f,0.f};

  #pragma unroll
  for (int k0i = 0; k0i < 4; ++k0i){
    #pragma unroll
    for (int ct = 0; ct < 8; ++ct){
      bf16x8 bw = *(const bf16x8*)(lw + k0i*4096 + ct*512 + lane*8);
      #pragma unroll
      for (int m = 0; m < 2; ++m)
        acc[m][ct] = __builtin_amdgcn_mfma_f32_16x16x32_bf16(af[m][k0i], bw, acc[m][ct], 0,0,0);
    }
  }

  float as_l[8], ad_l[8];
  #pragma unroll
  for (int ct = 0; ct < 8; ++ct){ as_l[ct] = att1[ct*16+ln]; ad_l[ct] = att2[ct*16+ln]; }
  #pragma unroll
  for (int m = 0; m < 2; ++m){
    #pragma unroll
    for (int r = 0; r < 4; ++r){
      int grow = waveRow + m*16 + q*4 + r;
      bool ok = grow < N_NODES;
      float ps = 0.f, pd = 0.f;
      #pragma unroll
      for (int ct = 0; ct < 8; ++ct){
        float v = acc[m][ct][r];
        if (ok) Cb[(size_t)grow*H + ct*16 + ln] = rne_bf16(v);
        ps += v * as_l[ct]; pd += v * ad_l[ct];
      }
      #pragma unroll
      for (int mk = 8; mk > 0; mk >>= 1){
        ps += __shfl_xor(ps, mk, 64);
        pd += __shfl_xor(pd, mk, 64);
      }
      if (ok && ln == 0){ a_s_out[grow] = ps; a_d_out[grow] = pd; }
    }
  }
}

// ---- fused dense1+dense2+readout, 32KB LDS / 4 blocks/CU --------------------
// relu1 transpose is wave-local (A2 rows lr = w*32+m*16+ln are within the
// wave's own 32 rows); slab lives inside dead lw. XOR-swizzle col^((lr&7)<<3).
__global__ __launch_bounds__(256, 4) void k_dense(
    const unsigned short* __restrict__ Ab,      // hb
    const unsigned short* __restrict__ Wf,      // W3 plane; W4 = Wf + 16384
    const float* __restrict__ b1, const float* __restrict__ b2,
    const float* __restrict__ wp, const int* __restrict__ batch,
    float* __restrict__ out)
{
  __shared__ unsigned short lw[16384];   // W3 -> relu1 slabs -> W4
  int tid  = threadIdx.x;
  int w    = tid >> 6;
  int lane = tid & 63;
  int q    = lane >> 4;
  int ln   = lane & 15;
  int waveRow = blockIdx.x*128 + w*32;

  // stage W3
  #pragma unroll
  for (int i = 0; i < 8; ++i){
    int base = (i*256 + w*64) * 8;
    __builtin_amdgcn_global_load_lds(
        (const __attribute__((address_space(1))) unsigned int*)(Wf + base + lane*8),
        (__attribute__((address_space(3))) unsigned int*)(lw + base),
        16, 0, 0);
  }
  bf16x8 af[2][4];
  #pragma unroll
  for (int m = 0; m < 2; ++m){
    int r = waveRow + m*16 + ln;
    if (r >= N_NODES) r = N_NODES - 1;
    const unsigned short* Ar = Ab + (size_t)r*H;
    #pragma unroll
    for (int k0i = 0; k0i < 4; ++k0i)
      af[m][k0i] = *(const bf16x8*)(Ar + k0i*32 + q*8);
  }
  __syncthreads();   // drains vmcnt -> W3 resident

  f32x4 acc[2][8];
  #pragma unroll
  for (int m = 0; m < 2; ++m)
    #pragma unroll
    for (int ct = 0; ct < 8; ++ct) acc[m][ct] = (f32x4){0.f,0.f,0.f,0.f};
  #pragma unroll
  for (int k0i = 0; k0i < 4; ++k0i){
    #pragma unroll
    for (int ct = 0; ct < 8; ++ct){
      bf16x8 bw = *(const bf16x8*)(lw + k0i*4096 + ct*512 + lane*8);
      #pragma unroll
      for (int m = 0; m < 2; ++m)
        acc[m][ct] = __builtin_amdgcn_mfma_f32_16x16x32_bf16(af[m][k0i], bw, acc[m][ct], 0,0,0);
    }
  }
  __syncthreads();   // all waves done reading W3 -> lw reusable

  // epilogue1: relu(acc + b1) -> per-wave 8KB slab (swizzled bf16)
  unsigned short* lh = lw + (w << 12);   // 4096 ushorts, wave-local rows 0..31
  float b1_l[8];
  #pragma unroll
  for (int ct = 0; ct < 8; ++ct) b1_l[ct] = b1[ct*16+ln];
  #pragma unroll
  for (int m = 0; m < 2; ++m){
    #pragma unroll
    for (int r = 0; r < 4; ++r){
      int lr = m*16 + q*4 + r;
      int sw = (lr & 7) << 3;
      #pragma unroll
      for (int ct = 0; ct < 8; ++ct){
        int col = ct*16 + ln;
        lh[lr*128 + (col ^ sw)] = rne_bf16(fmaxf(acc[m][ct][r] + b1_l[ct], 0.f));
      }
    }
  }
  __syncthreads();   // cross-lane LDS ordering (write -> read)

  // A2 fragments from slab (swizzled read, 16B-aligned b128)
  bf16x8 af2[2][4];
  #pragma unroll
  for (int m = 0; m < 2; ++m){
    int lr = m*16 + ln;
    int sw = (lr & 7) << 3;
    #pragma unroll
    for (int k0i = 0; k0i < 4; ++k0i)
      af2[m][k0i] = *(const bf16x8*)(lh + lr*128 + ((k0i*32 + q*8) ^ sw));
  }
  __syncthreads();   // all af2 reads done -> lw reusable for W4

  // stage W4 over lw
  #pragma unroll
  for (int i = 0; i < 8; ++i){
    int base = (i*256 + w*64) * 8;
    __builtin_amdgcn_global_load_lds(
        (const __attribute__((address_space(1))) unsigned int*)(Wf + 16384 + base + lane*8),
        (__attribute__((address_space(3))) unsigned int*)(lw + base),
        16, 0, 0);
  }
  __syncthreads();   // drains vmcnt -> W4 resident

  #pragma unroll
  for (int m = 0; m < 2; ++m)
    #pragma unroll
    for (int ct = 0; ct < 8; ++ct) acc[m][ct] = (f32x4){0.f,0.f,0.f,0.f};
  #pragma unroll
  for (int k0i = 0; k0i < 4; ++k0i){
    #pragma unroll
    for (int ct = 0; ct < 8; ++ct){
      bf16x8 bw = *(const bf16x8*)(lw + k0i*4096 + ct*512 + lane*8);
      #pragma unroll
      for (int m = 0; m < 2; ++m)
        acc[m][ct] = __builtin_amdgcn_mfma_f32_16x16x32_bf16(af2[m][k0i], bw, acc[m][ct], 0,0,0);
    }
  }

  // epilogue2: relu(acc + b2) . wp -> atomicAdd out[batch[row]]
  float b2_l[8], wp_l[8];
  #pragma unroll
  for (int ct = 0; ct < 8; ++ct){ b2_l[ct] = b2[ct*16+ln]; wp_l[ct] = wp[ct*16+ln]; }
  #pragma unroll
  for (int m = 0; m < 2; ++m){
    #pragma unroll
    for (int r = 0; r < 4; ++r){
      int grow = waveRow + m*16 + q*4 + r;
      bool ok = grow < N_NODES;
      float ps = 0.f;
      #pragma unroll
      for (int ct = 0; ct < 8; ++ct)
        ps += fmaxf(acc[m][ct][r] + b2_l[ct], 0.f) * wp_l[ct];
      #pragma unroll
      for (int mk = 8; mk > 0; mk >>= 1) ps += __shfl_xor(ps, mk, 64);
      if (ok && ln == 0) atomicAdd(&out[batch[grow]], ps);
    }
  }
}

// ---- aggregate: FOUR nodes per wave, 8 cols/lane (uint4 = 8 bf16) -----------
// R5-exact structure (best measured: 298.5 in-chain). Quarter h = lane>>4 owns
// node blk*16 + wid*4 + h; lane c = lane&15 covers cols 8c..8c+7. LDS-staged
// ls_s/ls_w (s staged EARLY, group-0 gathers issued before the wgt chain so
// the a_s-gather+exp overlaps them). VGPR ~56 -> 8 waves/SIMD (the R6/R7
// shuffle + dual-group prefetch pushed VGPR past the 64 step and halved
// occupancy -> +4us/layer; reverted per R7 post-mortem).
__global__ __launch_bounds__(256, 4) void k_aggregate(
    const uint4* __restrict__ xtb4, const float* __restrict__ a_s,
    const float* __restrict__ a_d, const int* __restrict__ csr_src,
    const float* __restrict__ csr_ea, const int* __restrict__ row_ptr,
    const int* __restrict__ deg, const float* __restrict__ scal, int l,
    const float* __restrict__ bias, uint4* __restrict__ hb4)
{
  __shared__ int   ls_s[4][4][16];
  __shared__ float ls_w[4][4][16];
  int wid  = threadIdx.x >> 6;
  int lane = threadIdx.x & 63;
  int h    = lane >> 4;          // quarter 0..3
  int c    = lane & 15;          // col group: cols 8c..8c+7
  int n    = blockIdx.x*16 + wid*4 + h;   // 6250*16 = 100000 exact
  if (n >= N_NODES) return;               // defensive (exact at current N)
  int beg = row_ptr[n];
  int d   = deg[n];              // >= 1 (self loop)
  float adn = a_d[n];
  float dl  = scal[32 + l];
  int v = d;
  v = max(v, __shfl_xor(v, 16, 64));
  v = max(v, __shfl_xor(v, 32, 64));
  int maxd = v;                  // wave-shared loop bound (all 4 quarters)

  float4 acA = make_float4(0.f,0.f,0.f,0.f);
  float4 acB = make_float4(0.f,0.f,0.f,0.f);
  float ss = 0.f;
  for (int base = 0; base < maxd; base += 16){
    int j = base + c;
    bool vld = (j < d);
    int s = 0; float eaj = 0.f;
    if (vld){
      int e = beg + j;
      s   = csr_src[e];                        // coalesced per quarter
      eaj = csr_ea[e];
    }
    ls_s[wid][h][c] = s;                       // s staged EARLY (wave-local)

    int cnt = (min(16, maxd - base) + 7) & ~7;

    // group 0: issue row gathers before the wgt chain
    uint4 xv[8];
    #pragma unroll
    for (int u = 0; u < 8; ++u)
      xv[u] = xtb4[(size_t)ls_s[wid][h][u]*(H/8) + c];

    // wgt chain (a_s gather + exp) overlaps the gathers above
    float wgt = 0.f;
    if (vld){
      float lg = a_s[s] + adn + dl*eaj;        // unstabilized exp is exact math
      lg = (lg > 0.f) ? lg : SLOPE*lg;
      wgt = __expf(lg);
    }
    ls_w[wid][h][c] = wgt;

    for (int j0 = 0; j0 < cnt; j0 += 8){
      if (j0){                                 // group 1: s,w already staged
        #pragma unroll
        for (int u = 0; u < 8; ++u)
          xv[u] = xtb4[(size_t)ls_s[wid][h][j0 + u]*(H/8) + c];
      }
      float w8[8];
      #pragma unroll
      for (int u = 0; u < 8; ++u) w8[u] = ls_w[wid][h][j0 + u];
      #pragma unroll
      for (int u = 0; u < 8; ++u){
        float wg = w8[u];
        acA.x += wg * __uint_as_float(xv[u].x << 16);
        acA.y += wg * __uint_as_float(xv[u].x & 0xFFFF0000u);
        acA.z += wg * __uint_as_float(xv[u].y << 16);
        acA.w += wg * __uint_as_float(xv[u].y & 0xFFFF0000u);
        acB.x += wg * __uint_as_float(xv[u].z << 16);
        acB.y += wg * __uint_as_float(xv[u].z & 0xFFFF0000u);
        acB.z += wg * __uint_as_float(xv[u].w << 16);
        acB.w += wg * __uint_as_float(xv[u].w & 0xFFFF0000u);
        ss    += wg;
      }
    }
  }

  float4 bvA = *(const float4*)(bias + c*8);
  float4 bvB = *(const float4*)(bias + c*8 + 4);
  float inv = 1.0f / ss;
  acA.x = acA.x*inv + bvA.x;
  acA.y = acA.y*inv + bvA.y;
  acA.z = acA.z*inv + bvA.z;
  acA.w = acA.w*inv + bvA.w;
  acB.x = acB.x*inv + bvB.x;
  acB.y = acB.y*inv + bvB.y;
  acB.z = acB.z*inv + bvB.z;
  acB.w = acB.w*inv + bvB.w;
  float sq = acA.x*acA.x + acA.y*acA.y + acA.z*acA.z + acA.w*acA.w
           + acB.x*acB.x + acB.y*acB.y + acB.z*acB.z + acB.w*acB.w;
  #pragma unroll
  for (int off = 8; off > 0; off >>= 1) sq += __shfl_xor(sq, off, 64);  // within quarter
  float rn = 1.0f / fmaxf(sqrtf(sq), 1e-12f);
  uint4 o;
  o.x = pack_bf16x2(acA.x*rn, acA.y*rn);
  o.y = pack_bf16x2(acA.z*rn, acA.w*rn);
  o.z = pack_bf16x2(acB.x*rn, acB.y*rn);
  o.w = pack_bf16x2(acB.z*rn, acB.w*rn);
  hb4[(size_t)n*(H/8) + c] = o;
}

// ---- launch -----------------------------------------------------------------
extern "C" void kernel_launch(void* const* d_in, const int* in_sizes, int n_in,
                              void* d_out, int out_size, void* d_ws, size_t ws_size,
                              hipStream_t stream) {
  const int*   x          = (const int*)  d_in[0];
  const int*   edge_index = (const int*)  d_in[1];
  const float* edge_attr  = (const float*)d_in[2];
  const int*   batch      = (const int*)  d_in[3];
  const float* emb        = (const float*)d_in[4];
  const float* gat_W      = (const float*)d_in[5];
  const float* att_src    = (const float*)d_in[6];
  const float* att_dst    = (const float*)d_in[7];
  const float* edge_W     = (const float*)d_in[8];
  const float* att_edge   = (const float*)d_in[9];
  const float* gat_b      = (const float*)d_in[10];
  const float* lin_W      = (const float*)d_in[11];
  const float* lin_b      = (const float*)d_in[12];
  const float* wp_W       = (const float*)d_in[13];
  const float* wp_b       = (const float*)d_in[14];
  float* out = (float*)d_out;

  // workspace layout — 16B-aligned bf16 arrays first, then 4B arrays
  unsigned short* hb  = (unsigned short*)d_ws;          // N*H bf16
  unsigned short* xtb = hb + (size_t)N_NODES*H;         // N*H bf16
  unsigned short* Wt  = xtb + (size_t)N_NODES*H;        // 5*16384 (RNE single plane)
  unsigned short* embb= Wt + 5*16384;                   // NV*H
  unsigned short* xt0b= embb + NV*H;                    // NV*H (vocab layer-0 rows)
  float* tabS   = (float*)(xt0b + NV*H);                // NV
  float* tabD   = tabS + NV;                            // NV
  float* a_s    = tabD + NV;                            // N
  float* a_d    = a_s + N_NODES;                        // N
  float* csr_ea = a_d + N_NODES;                        // E+N
  float* scal   = csr_ea + (N_EDGES + N_NODES);         // SCAL_N (zeroed)
  int*   deg    = (int*)(scal + SCAL_N);                // N (zeroed)
  int*   rank   = deg + N_NODES;                        // E+N
  int*   row_ptr= rank + (N_EDGES + N_NODES);           // N
  int*   csr_src= row_ptr + N_NODES;                    // E+N

  hipMemsetAsync(scal, 0, (size_t)(SCAL_N + N_NODES) * sizeof(float), stream);

  k_prep<<<PB_DEG, 256, 0, stream>>>(
      gat_W, lin_W, Wt, emb, embb, edge_attr, edge_W, att_edge, scal,
      wp_b, out, edge_index, deg, rank);
  // alloc scan + fused vocab layer-0 GEMM (1 extra block)
  k_alloc<<<NALLOC + 1, 256, 0, stream>>>(
      deg, row_ptr, (int*)&scal[48],
      embb, Wt, xt0b, att_src, att_dst, tabS, tabD);
  // scatter + fused layer-0 gather (xtb[n] = xt0b[x[n]], a_s/a_d tables)
  k_scatter<<<NSCAT + (N_NODES/16), 256, 0, stream>>>(
      edge_index, edge_attr, scal, row_ptr, rank, csr_src, csr_ea,
      x, (const uint4*)xt0b, tabS, tabD, (uint4*)xtb, a_s, a_d);

  const int gemm_grid = (N_NODES + 127) / 128;
  for (int l = 0; l < NLAYERS; ++l){
    if (l > 0)
      k_gemm<<<gemm_grid, 256, 0, stream>>>(
          hb, Wt + (size_t)l*16384, xtb,
          att_src + l*H, att_dst + l*H, a_s, a_d);
    k_aggregate<<<(N_NODES + 15)/16, 256, 0, stream>>>(
        (const uint4*)xtb, a_s, a_d, csr_src, csr_ea, row_ptr, deg,
        scal, l, gat_b + l*H, (uint4*)hb);
  }
  // fused dense1 + dense2 + readout (32KB LDS, 4 blocks/CU)
  k_dense<<<gemm_grid, 256, 0, stream>>>(
      hb, Wt + (size_t)3*16384, lin_b, lin_b + H, wp_W, batch, out);
}

// Round 9
// 294.051 us; speedup vs baseline: 1.0285x; 1.0056x over previous
//
#include <hip/hip_runtime.h>
#include <math.h>

#define N_NODES 100000
#define N_EDGES 400000
#define NG 2048
#define H 128
#define NV 100
#define NLAYERS 3
#define SLOPE 0.2f

// scal layout (64 floats = 256 B, all zeroed). Cross-XCD rule (R11 lesson):
// never mix atomic and plain stores on one 128B line within a dispatch.
//  [0]      ea_sum        (atomic, k_prep)
//  [32..34] dot_l         (atomic, k_prep)
//  [48]     alloc counter (atomic, k_alloc)
#define SCAL_N 64

typedef __attribute__((ext_vector_type(8))) short bf16x8;
typedef __attribute__((ext_vector_type(4))) float f32x4;

__device__ __forceinline__ float wave_reduce_sum(float v){
  #pragma unroll
  for (int off = 32; off > 0; off >>= 1) v += __shfl_xor(v, off, 64);
  return v;
}
__device__ __forceinline__ unsigned short rne_bf16(float f){
  unsigned int u = __float_as_uint(f);
  u += 0x7FFF + ((u >> 16) & 1);
  return (unsigned short)(u >> 16);
}
__device__ __forceinline__ unsigned int pack_bf16x2(float lo, float hi){
  return ((unsigned int)rne_bf16(hi) << 16) | rne_bf16(lo);
}

// ---- fused prep: convW | convE | out_init | dots | ea_sum | deg+rank --------
#define PB_CONVW 320                    // 5*16384/256 (single RNE plane)
#define PB_CONVE (PB_CONVW + 50)        // NV*H/256
#define PB_OUT   (PB_CONVE + 8)         // NG/256
#define PB_DOTS  (PB_OUT + 1)           // 3 waves in one block
#define PB_EASUM (PB_DOTS + 256)
#define PB_DEG   (PB_EASUM + 1954)      // (E+N)/256
__global__ __launch_bounds__(256) void k_prep(
    const float* __restrict__ gat_W, const float* __restrict__ lin_W,
    unsigned short* __restrict__ Wf,
    const float* __restrict__ emb, unsigned short* __restrict__ embb,
    const float* __restrict__ ea, const float* __restrict__ ew,
    const float* __restrict__ ae, float* __restrict__ scal,
    const float* __restrict__ wp_b, float* __restrict__ out,
    const int* __restrict__ ei, int* __restrict__ deg,
    int* __restrict__ rank)
{
  int b = blockIdx.x, tid = threadIdx.x;
  if (b < PB_CONVW){
    // W -> RNE bf16, MFMA B-fragment order:
    // idx = m*16384 + k0i*4096 + ct*512 + lane*8 + j
    // k = k0i*32 + (lane>>4)*8 + j, n = ct*16 + (lane&15)
    int i = b*256 + tid;
    int m   = i >> 14;
    int r   = i & 16383;
    int k0i = r >> 12;
    int r3  = r & 4095;
    int ct  = r3 >> 9;
    int r4  = r3 & 511;
    int lane= r4 >> 3;
    int j   = r4 & 7;
    int q = lane >> 4, ln = lane & 15;
    int k = k0i*32 + q*8 + j;
    int n = ct*16 + ln;
    const float* src = (m < 3) ? (gat_W + m*16384) : (lin_W + (m-3)*16384);
    Wf[i] = rne_bf16(src[k*H + n]);
  } else if (b < PB_CONVE){
    int i = (b - PB_CONVW)*256 + tid;
    if (i < NV*H) embb[i] = rne_bf16(emb[i]);
  } else if (b < PB_OUT){
    int g = (b - PB_CONVE)*256 + tid;
    if (g < NG) out[g] = wp_b[0];
  } else if (b < PB_DOTS){
    int l = tid >> 6, ln = tid & 63;
    if (l < NLAYERS){
      float p = ew[l*H + ln]*ae[l*H + ln] + ew[l*H + ln + 64]*ae[l*H + ln + 64];
      p = wave_reduce_sum(p);
      if (ln == 0) atomicAdd(&scal[32 + l], p);
    }
  } else if (b < PB_EASUM){
    int i = (b - PB_DOTS)*256 + tid;
    int stride = 256*256;
    float v = 0.f;
    for (; i < N_EDGES; i += stride) v += ea[i];
    v = wave_reduce_sum(v);
    if ((tid & 63) == 0) atomicAdd(&scal[0], v);
  } else {
    // deg count; the return value IS the edge's rank within its dst bucket —
    // stored so k_scatter needs no second atomic pass.
    int i = (b - PB_EASUM)*256 + tid;
    if (i < N_EDGES + N_NODES){
      int d = (i < N_EDGES) ? ei[N_EDGES + i] : (i - N_EDGES);
      rank[i] = atomicAdd(&deg[d], 1);
    }
  }
}

// ---- alloc (block scan + one atomic) | fused vocab GEMM ---------------------
// Layer-0 projection has only NV=100 distinct rows: one extra block runs the
// EXACT gemm instruction sequence on the 100 vocab rows (same fragments ->
// same MFMA bits -> same epilogue reduce order => bitwise identical to a
// full-N gemm), producing xt0b + per-vocab a_s/a_d tables. The full-N
// result is then a gather-copy (fused into k_scatter). [validated bit-exact R7]
#define NALLOC ((N_NODES + 255)/256)    // 391
__global__ __launch_bounds__(256) void k_alloc(
    const int* __restrict__ deg, int* __restrict__ row_ptr, int* __restrict__ counter,
    const unsigned short* __restrict__ embb, const unsigned short* __restrict__ Wf,
    unsigned short* __restrict__ xt0b, const float* __restrict__ att1,
    const float* __restrict__ att2, float* __restrict__ tabS, float* __restrict__ tabD)
{
  __shared__ unsigned short lw[16384];
  __shared__ int wsum[4];
  __shared__ int base_s;
  if (blockIdx.x < NALLOC){
    int n = blockIdx.x * 256 + threadIdx.x;
    int d = (n < N_NODES) ? deg[n] : 0;
    int lane = threadIdx.x & 63, wid = threadIdx.x >> 6;
    int v = d;
    #pragma unroll
    for (int off = 1; off < 64; off <<= 1){
      int u = __shfl_up(v, off, 64);
      if (lane >= off) v += u;
    }
    if (lane == 63) wsum[wid] = v;
    __syncthreads();
    if (threadIdx.x == 0){
      int t0 = wsum[0], t1 = wsum[1], t2 = wsum[2], t3 = wsum[3];
      base_s = atomicAdd(counter, t0 + t1 + t2 + t3);
      wsum[0] = 0; wsum[1] = t0; wsum[2] = t0 + t1; wsum[3] = t0 + t1 + t2;
    }
    __syncthreads();
    if (n < N_NODES) row_ptr[n] = base_s + wsum[wid] + (v - d);
    return;
  }

  // ---- vocab GEMM block (blockIdx.x == NALLOC) ----
  int tid  = threadIdx.x;
  int w    = tid >> 6;
  int lane = tid & 63;
  int q    = lane >> 4;
  int ln   = lane & 15;
  int waveRow = w*32;

  #pragma unroll
  for (int i = 0; i < 8; ++i){
    int base = (i*256 + w*64) * 8;
    __builtin_amdgcn_global_load_lds(
        (const __attribute__((address_space(1))) unsigned int*)(Wf + base + lane*8),
        (__attribute__((address_space(3))) unsigned int*)(lw + base),
        16, 0, 0);
  }
  bf16x8 af[2][4];
  #pragma unroll
  for (int m = 0; m < 2; ++m){
    int r = waveRow + m*16 + ln;
    if (r >= NV) r = NV - 1;                 // clamp
    const unsigned short* Ar = embb + (size_t)r*H;
    #pragma unroll
    for (int k0i = 0; k0i < 4; ++k0i)
      af[m][k0i] = *(const bf16x8*)(Ar + k0i*32 + q*8);
  }
  __syncthreads();

  f32x4 acc[2][8];
  #pragma unroll
  for (int m = 0; m < 2; ++m)
    #pragma unroll
    for (int ct = 0; ct < 8; ++ct) acc[m][ct] = (f32x4){0.f,0.f,0.f,0.f};
  #pragma unroll
  for (int k0i = 0; k0i < 4; ++k0i){
    #pragma unroll
    for (int ct = 0; ct < 8; ++ct){
      bf16x8 bw = *(const bf16x8*)(lw + k0i*4096 + ct*512 + lane*8);
      #pragma unroll
      for (int m = 0; m < 2; ++m)
        acc[m][ct] = __builtin_amdgcn_mfma_f32_16x16x32_bf16(af[m][k0i], bw, acc[m][ct], 0,0,0);
    }
  }

  float as_l[8], ad_l[8];
  #pragma unroll
  for (int ct = 0; ct < 8; ++ct){ as_l[ct] = att1[ct*16+ln]; ad_l[ct] = att2[ct*16+ln]; }
  #pragma unroll
  for (int m = 0; m < 2; ++m){
    #pragma unroll
    for (int r = 0; r < 4; ++r){
      int grow = waveRow + m*16 + q*4 + r;
      bool ok = grow < NV;
      float ps = 0.f, pd = 0.f;
      #pragma unroll
      for (int ct = 0; ct < 8; ++ct){
        float v = acc[m][ct][r];
        if (ok) xt0b[(size_t)grow*H + ct*16 + ln] = rne_bf16(v);
        ps += v * as_l[ct]; pd += v * ad_l[ct];
      }
      #pragma unroll
      for (int mk = 8; mk > 0; mk >>= 1){
        ps += __shfl_xor(ps, mk, 64);
        pd += __shfl_xor(pd, mk, 64);
      }
      if (ok && ln == 0){ tabS[grow] = ps; tabD[grow] = pd; }
    }
  }
}

// ---- scatter (atomic-free, rank-based) | fused layer-0 gather ---------------
#define NSCAT ((N_EDGES + N_NODES + 255)/256)   // 1954
__global__ void k_scatter(const int* __restrict__ ei, const float* __restrict__ ea,
                          const float* __restrict__ scal, const int* __restrict__ row_ptr,
                          const int* __restrict__ rank, int* __restrict__ csr_src,
                          float* __restrict__ csr_ea,
                          const int* __restrict__ x, const uint4* __restrict__ xt0b4,
                          const float* __restrict__ tabS, const float* __restrict__ tabD,
                          uint4* __restrict__ xtb4, float* __restrict__ a_s,
                          float* __restrict__ a_d){
  int b = blockIdx.x;
  if (b < NSCAT){
    int i = b * 256 + threadIdx.x;
    if (i >= N_EDGES + N_NODES) return;
    int s, d; float v;
    if (i < N_EDGES){ s = ei[i]; d = ei[N_EDGES + i]; v = ea[i]; }
    else            { s = d = i - N_EDGES; v = scal[0] * (1.0f / N_EDGES); }  // ea_mean
    int pos = row_ptr[d] + rank[i];
    csr_src[pos] = s;
    csr_ea[pos]  = v;
    return;
  }
  // layer-0 gather: xtb[n] = xt0b[x[n]], a_s/a_d from vocab tables
  int gb = b - NSCAT;                        // [0, 6250)
  int t  = threadIdx.x;
  int n  = gb*16 + (t >> 4);                 // 6250*16 = 100000 exact
  int c  = t & 15;
  if (n >= N_NODES) return;                  // defensive (exact at current N)
  int v  = x[n];
  xtb4[(size_t)n*(H/8) + c] = xt0b4[(size_t)v*(H/8) + c];
  if (c == 0)      a_s[n] = tabS[v];
  else if (c == 1) a_d[n] = tabD[v];
}

// ---- MFMA GEMM (layers 1,2): 64-row block tile, 16-row wave tile ------------
// R9 change: 128-row tiles gave grid=782 = 3.05 blocks/CU resident -> W-stage
// latency exposed with only 12 waves/CU. 64-row tiles: grid=1563, 5 blocks/CU
// (LDS 32KB caps at 5) = 20 waves/CU during staging. W-traffic doubles to
// 50MB but is L2-hot (~1.5us @ 34TB/s). Per-row math is the identical MFMA
// fragment/accumulate/epilogue sequence (m=1 tile) -> bitwise identical.
__global__ __launch_bounds__(256, 4) void k_gemm(
    const unsigned short* __restrict__ Ab,
    const unsigned short* __restrict__ Wf,      // fragment-ordered, 16384 ushorts
    unsigned short* __restrict__ Cb,
    const float* __restrict__ att1, const float* __restrict__ att2,
    float* __restrict__ a_s_out, float* __restrict__ a_d_out)
{
  __shared__ unsigned short lw[16384];   // 32 KB single plane
  int tid  = threadIdx.x;
  int w    = tid >> 6;
  int lane = tid & 63;
  int q    = lane >> 4;
  int ln   = lane & 15;
  int waveRow = blockIdx.x*64 + w*16;

  #pragma unroll
  for (int i = 0; i < 8; ++i){
    int base = (i*256 + w*64) * 8;               // ushort offset, wave-uniform
    __builtin_amdgcn_global_load_lds(
        (const __attribute__((address_space(1))) unsigned int*)(Wf + base + lane*8),
        (__attribute__((address_space(3))) unsigned int*)(lw + base),
        16, 0, 0);
  }

  bf16x8 af[4];
  {
    int r = waveRow + ln;
    if (r >= N_NODES) r = N_NODES - 1;
    const unsigned short* Ar = Ab + (size_t)r*H;
    #pragma unroll
    for (int k0i = 0; k0i < 4; ++k0i)
      af[k0i] = *(const bf16x8*)(Ar + k0i*32 + q*8);
  }
  __syncthreads();   // drains vmcnt (incl. global_load_lds) before ds_read

  f32x4 acc[8];
  #pragma unroll
  for (int ct = 0; ct < 8; ++ct) acc[ct] = (f32x4){0.f,0.f,0.f,0.f};

  #pragma unroll
  for (int k0i = 0; k0i < 4; ++k0i){
    #pragma unroll
    for (int ct = 0; ct < 8; ++ct){
      bf16x8 bw = *(const bf16x8*)(lw + k0i*4096 + ct*512 + lane*8);
      acc[ct] = __builtin_amdgcn_mfma_f32_16x16x32_bf16(af[k0i], bw, acc[ct], 0,0,0);
    }
  }

  float as_l[8], ad_l[8];
  #pragma unroll
  for (int ct = 0; ct < 8; ++ct){ as_l[ct] = att1[ct*16+ln]; ad_l[ct] = att2[ct*16+ln]; }
  #pragma unroll
  for (int r = 0; r < 4; ++r){
    int grow = waveRow + q*4 + r;
    bool ok = grow < N_NODES;
    float ps = 0.f, pd = 0.f;
    #pragma unroll
    for (int ct = 0; ct < 8; ++ct){
      float v = acc[ct][r];
      if (ok) Cb[(size_t)grow*H + ct*16 + ln] = rne_bf16(v);
      ps += v * as_l[ct]; pd += v * ad_l[ct];
    }
    #pragma unroll
    for (int mk = 8; mk > 0; mk >>= 1){
      ps += __shfl_xor(ps, mk, 64);
      pd += __shfl_xor(pd, mk, 64);
    }
    if (ok && ln == 0){ a_s_out[grow] = ps; a_d_out[grow] = pd; }
  }
}

// ---- fused dense1+dense2+readout, 32KB LDS / 4 blocks/CU --------------------
// relu1 transpose is wave-local (A2 rows lr = w*32+m*16+ln are within the
// wave's own 32 rows); slab lives inside dead lw. XOR-swizzle col^((lr&7)<<3).
__global__ __launch_bounds__(256, 4) void k_dense(
    const unsigned short* __restrict__ Ab,      // hb
    const unsigned short* __restrict__ Wf,      // W3 plane; W4 = Wf + 16384
    const float* __restrict__ b1, const float* __restrict__ b2,
    const float* __restrict__ wp, const int* __restrict__ batch,
    float* __restrict__ out)
{
  __shared__ unsigned short lw[16384];   // W3 -> relu1 slabs -> W4
  int tid  = threadIdx.x;
  int w    = tid >> 6;
  int lane = tid & 63;
  int q    = lane >> 4;
  int ln   = lane & 15;
  int waveRow = blockIdx.x*128 + w*32;

  // stage W3
  #pragma unroll
  for (int i = 0; i < 8; ++i){
    int base = (i*256 + w*64) * 8;
    __builtin_amdgcn_global_load_lds(
        (const __attribute__((address_space(1))) unsigned int*)(Wf + base + lane*8),
        (__attribute__((address_space(3))) unsigned int*)(lw + base),
        16, 0, 0);
  }
  bf16x8 af[2][4];
  #pragma unroll
  for (int m = 0; m < 2; ++m){
    int r = waveRow + m*16 + ln;
    if (r >= N_NODES) r = N_NODES - 1;
    const unsigned short* Ar = Ab + (size_t)r*H;
    #pragma unroll
    for (int k0i = 0; k0i < 4; ++k0i)
      af[m][k0i] = *(const bf16x8*)(Ar + k0i*32 + q*8);
  }
  __syncthreads();   // drains vmcnt -> W3 resident

  f32x4 acc[2][8];
  #pragma unroll
  for (int m = 0; m < 2; ++m)
    #pragma unroll
    for (int ct = 0; ct < 8; ++ct) acc[m][ct] = (f32x4){0.f,0.f,0.f,0.f};
  #pragma unroll
  for (int k0i = 0; k0i < 4; ++k0i){
    #pragma unroll
    for (int ct = 0; ct < 8; ++ct){
      bf16x8 bw = *(const bf16x8*)(lw + k0i*4096 + ct*512 + lane*8);
      #pragma unroll
      for (int m = 0; m < 2; ++m)
        acc[m][ct] = __builtin_amdgcn_mfma_f32_16x16x32_bf16(af[m][k0i], bw, acc[m][ct], 0,0,0);
    }
  }
  __syncthreads();   // all waves done reading W3 -> lw reusable

  // epilogue1: relu(acc + b1) -> per-wave 8KB slab (swizzled bf16)
  unsigned short* lh = lw + (w << 12);   // 4096 ushorts, wave-local rows 0..31
  float b1_l[8];
  #pragma unroll
  for (int ct = 0; ct < 8; ++ct) b1_l[ct] = b1[ct*16+ln];
  #pragma unroll
  for (int m = 0; m < 2; ++m){
    #pragma unroll
    for (int r = 0; r < 4; ++r){
      int lr = m*16 + q*4 + r;
      int sw = (lr & 7) << 3;
      #pragma unroll
      for (int ct = 0; ct < 8; ++ct){
        int col = ct*16 + ln;
        lh[lr*128 + (col ^ sw)] = rne_bf16(fmaxf(acc[m][ct][r] + b1_l[ct], 0.f));
      }
    }
  }
  __syncthreads();   // cross-lane LDS ordering (write -> read)

  // A2 fragments from slab (swizzled read, 16B-aligned b128)
  bf16x8 af2[2][4];
  #pragma unroll
  for (int m = 0; m < 2; ++m){
    int lr = m*16 + ln;
    int sw = (lr & 7) << 3;
    #pragma unroll
    for (int k0i = 0; k0i < 4; ++k0i)
      af2[m][k0i] = *(const bf16x8*)(lh + lr*128 + ((k0i*32 + q*8) ^ sw));
  }
  __syncthreads();   // all af2 reads done -> lw reusable for W4

  // stage W4 over lw
  #pragma unroll
  for (int i = 0; i < 8; ++i){
    int base = (i*256 + w*64) * 8;
    __builtin_amdgcn_global_load_lds(
        (const __attribute__((address_space(1))) unsigned int*)(Wf + 16384 + base + lane*8),
        (__attribute__((address_space(3))) unsigned int*)(lw + base),
        16, 0, 0);
  }
  __syncthreads();   // drains vmcnt -> W4 resident

  #pragma unroll
  for (int m = 0; m < 2; ++m)
    #pragma unroll
    for (int ct = 0; ct < 8; ++ct) acc[m][ct] = (f32x4){0.f,0.f,0.f,0.f};
  #pragma unroll
  for (int k0i = 0; k0i < 4; ++k0i){
    #pragma unroll
    for (int ct = 0; ct < 8; ++ct){
      bf16x8 bw = *(const bf16x8*)(lw + k0i*4096 + ct*512 + lane*8);
      #pragma unroll
      for (int m = 0; m < 2; ++m)
        acc[m][ct] = __builtin_amdgcn_mfma_f32_16x16x32_bf16(af2[m][k0i], bw, acc[m][ct], 0,0,0);
    }
  }

  // epilogue2: relu(acc + b2) . wp -> atomicAdd out[batch[row]]
  float b2_l[8], wp_l[8];
  #pragma unroll
  for (int ct = 0; ct < 8; ++ct){ b2_l[ct] = b2[ct*16+ln]; wp_l[ct] = wp[ct*16+ln]; }
  #pragma unroll
  for (int m = 0; m < 2; ++m){
    #pragma unroll
    for (int r = 0; r < 4; ++r){
      int grow = waveRow + m*16 + q*4 + r;
      bool ok = grow < N_NODES;
      float ps = 0.f;
      #pragma unroll
      for (int ct = 0; ct < 8; ++ct)
        ps += fmaxf(acc[m][ct][r] + b2_l[ct], 0.f) * wp_l[ct];
      #pragma unroll
      for (int mk = 8; mk > 0; mk >>= 1) ps += __shfl_xor(ps, mk, 64);
      if (ok && ln == 0) atomicAdd(&out[batch[grow]], ps);
    }
  }
}

// ---- aggregate: FOUR nodes per wave, 8 cols/lane (uint4 = 8 bf16) -----------
// R5-exact structure (best measured). Quarter h = lane>>4 owns node
// blk*16 + wid*4 + h; lane c = lane&15 covers cols 8c..8c+7. LDS-staged
// ls_s/ls_w (s staged EARLY, group-0 gathers issued before the wgt chain so
// the a_s-gather+exp overlaps them). VGPR ~56 -> 8 waves/SIMD (R7's deeper
// prefetch crossed the 64-VGPR step and halved occupancy; reverted).
__global__ __launch_bounds__(256, 4) void k_aggregate(
    const uint4* __restrict__ xtb4, const float* __restrict__ a_s,
    const float* __restrict__ a_d, const int* __restrict__ csr_src,
    const float* __restrict__ csr_ea, const int* __restrict__ row_ptr,
    const int* __restrict__ deg, const float* __restrict__ scal, int l,
    const float* __restrict__ bias, uint4* __restrict__ hb4)
{
  __shared__ int   ls_s[4][4][16];
  __shared__ float ls_w[4][4][16];
  int wid  = threadIdx.x >> 6;
  int lane = threadIdx.x & 63;
  int h    = lane >> 4;          // quarter 0..3
  int c    = lane & 15;          // col group: cols 8c..8c+7
  int n    = blockIdx.x*16 + wid*4 + h;   // 6250*16 = 100000 exact
  if (n >= N_NODES) return;               // defensive (exact at current N)
  int beg = row_ptr[n];
  int d   = deg[n];              // >= 1 (self loop)
  float adn = a_d[n];
  float dl  = scal[32 + l];
  int v = d;
  v = max(v, __shfl_xor(v, 16, 64));
  v = max(v, __shfl_xor(v, 32, 64));
  int maxd = v;                  // wave-shared loop bound (all 4 quarters)

  float4 acA = make_float4(0.f,0.f,0.f,0.f);
  float4 acB = make_float4(0.f,0.f,0.f,0.f);
  float ss = 0.f;
  for (int base = 0; base < maxd; base += 16){
    int j = base + c;
    bool vld = (j < d);
    int s = 0; float eaj = 0.f;
    if (vld){
      int e = beg + j;
      s   = csr_src[e];                        // coalesced per quarter
      eaj = csr_ea[e];
    }
    ls_s[wid][h][c] = s;                       // s staged EARLY (wave-local)

    int cnt = (min(16, maxd - base) + 7) & ~7;

    // group 0: issue row gathers before the wgt chain
    uint4 xv[8];
    #pragma unroll
    for (int u = 0; u < 8; ++u)
      xv[u] = xtb4[(size_t)ls_s[wid][h][u]*(H/8) + c];

    // wgt chain (a_s gather + exp) overlaps the gathers above
    float wgt = 0.f;
    if (vld){
      float lg = a_s[s] + adn + dl*eaj;        // unstabilized exp is exact math
      lg = (lg > 0.f) ? lg : SLOPE*lg;
      wgt = __expf(lg);
    }
    ls_w[wid][h][c] = wgt;

    for (int j0 = 0; j0 < cnt; j0 += 8){
      if (j0){                                 // group 1: s,w already staged
        #pragma unroll
        for (int u = 0; u < 8; ++u)
          xv[u] = xtb4[(size_t)ls_s[wid][h][j0 + u]*(H/8) + c];
      }
      float w8[8];
      #pragma unroll
      for (int u = 0; u < 8; ++u) w8[u] = ls_w[wid][h][j0 + u];
      #pragma unroll
      for (int u = 0; u < 8; ++u){
        float wg = w8[u];
        acA.x += wg * __uint_as_float(xv[u].x << 16);
        acA.y += wg * __uint_as_float(xv[u].x & 0xFFFF0000u);
        acA.z += wg * __uint_as_float(xv[u].y << 16);
        acA.w += wg * __uint_as_float(xv[u].y & 0xFFFF0000u);
        acB.x += wg * __uint_as_float(xv[u].z << 16);
        acB.y += wg * __uint_as_float(xv[u].z & 0xFFFF0000u);
        acB.z += wg * __uint_as_float(xv[u].w << 16);
        acB.w += wg * __uint_as_float(xv[u].w & 0xFFFF0000u);
        ss    += wg;
      }
    }
  }

  float4 bvA = *(const float4*)(bias + c*8);
  float4 bvB = *(const float4*)(bias + c*8 + 4);
  float inv = 1.0f / ss;
  acA.x = acA.x*inv + bvA.x;
  acA.y = acA.y*inv + bvA.y;
  acA.z = acA.z*inv + bvA.z;
  acA.w = acA.w*inv + bvA.w;
  acB.x = acB.x*inv + bvB.x;
  acB.y = acB.y*inv + bvB.y;
  acB.z = acB.z*inv + bvB.z;
  acB.w = acB.w*inv + bvB.w;
  float sq = acA.x*acA.x + acA.y*acA.y + acA.z*acA.z + acA.w*acA.w
           + acB.x*acB.x + acB.y*acB.y + acB.z*acB.z + acB.w*acB.w;
  #pragma unroll
  for (int off = 8; off > 0; off >>= 1) sq += __shfl_xor(sq, off, 64);  // within quarter
  float rn = 1.0f / fmaxf(sqrtf(sq), 1e-12f);
  uint4 o;
  o.x = pack_bf16x2(acA.x*rn, acA.y*rn);
  o.y = pack_bf16x2(acA.z*rn, acA.w*rn);
  o.z = pack_bf16x2(acB.x*rn, acB.y*rn);
  o.w = pack_bf16x2(acB.z*rn, acB.w*rn);
  hb4[(size_t)n*(H/8) + c] = o;
}

// ---- launch -----------------------------------------------------------------
extern "C" void kernel_launch(void* const* d_in, const int* in_sizes, int n_in,
                              void* d_out, int out_size, void* d_ws, size_t ws_size,
                              hipStream_t stream) {
  const int*   x          = (const int*)  d_in[0];
  const int*   edge_index = (const int*)  d_in[1];
  const float* edge_attr  = (const float*)d_in[2];
  const int*   batch      = (const int*)  d_in[3];
  const float* emb        = (const float*)d_in[4];
  const float* gat_W      = (const float*)d_in[5];
  const float* att_src    = (const float*)d_in[6];
  const float* att_dst    = (const float*)d_in[7];
  const float* edge_W     = (const float*)d_in[8];
  const float* att_edge   = (const float*)d_in[9];
  const float* gat_b      = (const float*)d_in[10];
  const float* lin_W      = (const float*)d_in[11];
  const float* lin_b      = (const float*)d_in[12];
  const float* wp_W       = (const float*)d_in[13];
  const float* wp_b       = (const float*)d_in[14];
  float* out = (float*)d_out;

  // workspace layout — 16B-aligned bf16 arrays first, then 4B arrays
  unsigned short* hb  = (unsigned short*)d_ws;          // N*H bf16
  unsigned short* xtb = hb + (size_t)N_NODES*H;         // N*H bf16
  unsigned short* Wt  = xtb + (size_t)N_NODES*H;        // 5*16384 (RNE single plane)
  unsigned short* embb= Wt + 5*16384;                   // NV*H
  unsigned short* xt0b= embb + NV*H;                    // NV*H (vocab layer-0 rows)
  float* tabS   = (float*)(xt0b + NV*H);                // NV
  float* tabD   = tabS + NV;                            // NV
  float* a_s    = tabD + NV;                            // N
  float* a_d    = a_s + N_NODES;                        // N
  float* csr_ea = a_d + N_NODES;                        // E+N
  float* scal   = csr_ea + (N_EDGES + N_NODES);         // SCAL_N (zeroed)
  int*   deg    = (int*)(scal + SCAL_N);                // N (zeroed)
  int*   rank   = deg + N_NODES;                        // E+N
  int*   row_ptr= rank + (N_EDGES + N_NODES);           // N
  int*   csr_src= row_ptr + N_NODES;                    // E+N

  hipMemsetAsync(scal, 0, (size_t)(SCAL_N + N_NODES) * sizeof(float), stream);

  k_prep<<<PB_DEG, 256, 0, stream>>>(
      gat_W, lin_W, Wt, emb, embb, edge_attr, edge_W, att_edge, scal,
      wp_b, out, edge_index, deg, rank);
  // alloc scan + fused vocab layer-0 GEMM (1 extra block)
  k_alloc<<<NALLOC + 1, 256, 0, stream>>>(
      deg, row_ptr, (int*)&scal[48],
      embb, Wt, xt0b, att_src, att_dst, tabS, tabD);
  // scatter + fused layer-0 gather (xtb[n] = xt0b[x[n]], a_s/a_d tables)
  k_scatter<<<NSCAT + (N_NODES/16), 256, 0, stream>>>(
      edge_index, edge_attr, scal, row_ptr, rank, csr_src, csr_ea,
      x, (const uint4*)xt0b, tabS, tabD, (uint4*)xtb, a_s, a_d);

  const int gemm_grid = (N_NODES + 63) / 64;    // 64-row tiles (R9)
  const int dense_grid = (N_NODES + 127) / 128;
  for (int l = 0; l < NLAYERS; ++l){
    if (l > 0)
      k_gemm<<<gemm_grid, 256, 0, stream>>>(
          hb, Wt + (size_t)l*16384, xtb,
          att_src + l*H, att_dst + l*H, a_s, a_d);
    k_aggregate<<<(N_NODES + 15)/16, 256, 0, stream>>>(
        (const uint4*)xtb, a_s, a_d, csr_src, csr_ea, row_ptr, deg,
        scal, l, gat_b + l*H, (uint4*)hb);
  }
  // fused dense1 + dense2 + readout (32KB LDS, 4 blocks/CU)
  k_dense<<<dense_grid, 256, 0, stream>>>(
      hb, Wt + (size_t)3*16384, lin_b, lin_b + H, wp_W, batch, out);
}